// Round 6
// baseline (548.063 us; speedup 1.0000x reference)
//
#include <hip/hip_runtime.h>
#include <hip/hip_cooperative_groups.h>
namespace cg = cooperative_groups;

#define BATCH 16
#define CH    64
#define HW_PX 65536
#define GRIDF 768                 // cooperative grid: 3 blocks/CU x 256 CUs
#define BPB   (GRIDF / BATCH)     // 48 blocks per batch
#define TPB   1024                // 64-px tiles per batch
#define PARTIAL_STRIDE 4160       // 4096 cov partial + 64 channel sums
// fallback (round-5) config:
#define NB2 128
#define PX2 512
#define TPX 64
#define NT2 (PX2 / TPX)

using bf16x8 = __attribute__((ext_vector_type(8))) short;
using f32x16 = __attribute__((ext_vector_type(16))) float;
using f32x4  = __attribute__((ext_vector_type(4))) float;

__device__ inline unsigned short bf16_rne(float f) {
    unsigned int u = __builtin_bit_cast(unsigned int, f);
    u += 0x7FFFu + ((u >> 16) & 1u);
    return (unsigned short)(u >> 16);
}
__device__ inline float bf16_f32(unsigned short s) {
    unsigned int u = ((unsigned int)s) << 16;
    return __builtin_bit_cast(float, u);
}
__device__ inline int sw_idx(int row, int col) {
    return row * 64 + ((((col >> 3) ^ (row & 7)) << 3) | (col & 7));
}
__device__ inline bf16x8 ld_frag8(const short* m, int row, int o) {
    return *(const bf16x8*)&m[row * 64 + ((o ^ (row & 7)) << 3)];
}
__device__ inline void mm_quad_hilo(f32x16& acc,
        const short* Ah, const short* Al,
        const short* Bh, const short* Bl,
        int ra, int rb, int lane) {
    #pragma unroll
    for (int kc = 0; kc < 4; ++kc) {
        int o = kc * 2 + (lane >> 5);
        bf16x8 ah = ld_frag8(Ah, ra, o);
        bf16x8 al = ld_frag8(Al, ra, o);
        bf16x8 bh = ld_frag8(Bh, rb, o);
        bf16x8 bl = ld_frag8(Bl, rb, o);
        acc = __builtin_amdgcn_mfma_f32_32x32x16_bf16(ah, bh, acc, 0, 0, 0);
        acc = __builtin_amdgcn_mfma_f32_32x32x16_bf16(ah, bl, acc, 0, 0, 0);
        acc = __builtin_amdgcn_mfma_f32_32x32x16_bf16(al, bh, acc, 0, 0, 0);
    }
}
__device__ inline void wb_hilo(short* Mh, short* Ml, const f32x16& v,
                               int r, int cq, int lane, float scale, float diag) {
    #pragma unroll
    for (int reg = 0; reg < 16; ++reg) {
        int row = 32 * r + (reg & 3) + 8 * (reg >> 2) + 4 * (lane >> 5);
        int col = 32 * cq + (lane & 31);
        float f = v[reg] * scale + ((row == col) ? diag : 0.0f);
        unsigned short hi = bf16_rne(f);
        float lo = f - bf16_f32(hi);
        int idx = sw_idx(row, col);
        Mh[idx] = (short)hi;
        Ml[idx] = (short)bf16_rne(lo);
    }
}

// ==================== fused cooperative kernel ====================
// LDS union (SM_BYTES = 50176, 3 blocks/CU):
//  phase1: xs 2x8KB @0, fsum 1KB @16384
//  ns    : Yh@0 Yl@8192 Zh@16384 Zl@24576 Ph@32768 Pl@40960 (Cf fp32 aliases Ph..Pl)
//  comb  : Yh/Yl/Zh/Zl @0..32768, Mf (64x66 f32) @32768 (ends 49664)
//  phase2: msh @49664; csh @49920
#define SM_BYTES 50176

__global__ __launch_bounds__(256, 3) void wct_fused(
        const float* __restrict__ x, const int* __restrict__ perm,
        const float* __restrict__ alpha, float* __restrict__ out,
        float* __restrict__ partial, float* __restrict__ cov,
        float* __restrict__ meanv, float* __restrict__ Ym,
        float* __restrict__ Zm, float* __restrict__ Am,
        float* __restrict__ ev)
{
    cg::grid_group gg = cg::this_grid();
    __shared__ __align__(16) unsigned char smem[SM_BYTES];
    const int w = blockIdx.x;
    const int t = threadIdx.x;
    const int lane = t & 63;
    const int wave = t >> 6;
    const int b = w / BPB, j = w % BPB;

    // ---------------- phase 1: cov partials ----------------
    {
        short* xs = (short*)smem;                 // [2][4096] bf16, swizzled [ch][px]
        float* fsum = (float*)(smem + 16384);
        const int r = wave >> 1, cq = wave & 1;
        const int t0 = (j * TPB) / BPB, t1 = ((j + 1) * TPB) / BPB;
        const size_t xb = (size_t)b * HW_PX * CH;
        const int s_ch = t & 63, s_og = t >> 6;
        f32x16 acc;
        #pragma unroll
        for (int i = 0; i < 16; ++i) acc[i] = 0.0f;
        float csum = 0.0f;
        auto stage1 = [&](int buf, int tile) {
            const size_t tb = xb + (size_t)tile * 64 * CH;
            #pragma unroll
            for (int p = 0; p < 2; ++p) {
                const int o = s_og + 4 * p;
                bf16x8 wv;
                #pragma unroll
                for (int jj = 0; jj < 8; ++jj) {
                    float v = x[tb + (size_t)(o * 8 + jj) * CH + s_ch];
                    csum += v;
                    wv[jj] = (short)bf16_rne(v);
                }
                *(bf16x8*)&xs[buf * 4096 + s_ch * 64 + ((o ^ (s_ch & 7)) << 3)] = wv;
            }
        };
        stage1(0, t0);
        __syncthreads();
        const int ra = 32 * r + (lane & 31);
        const int rb = 32 * cq + (lane & 31);
        const int nt = t1 - t0;
        for (int k = 0; k < nt; ++k) {
            const int cur = k & 1;
            if (k + 1 < nt) stage1(cur ^ 1, t0 + k + 1);
            #pragma unroll
            for (int kc = 0; kc < 4; ++kc) {
                const int o = kc * 2 + (lane >> 5);
                bf16x8 af = ld_frag8(xs + cur * 4096, ra, o);
                bf16x8 bg = ld_frag8(xs + cur * 4096, rb, o);
                acc = __builtin_amdgcn_mfma_f32_32x32x16_bf16(af, bg, acc, 0, 0, 0);
            }
            __syncthreads();
        }
        float* myp = partial + (size_t)w * PARTIAL_STRIDE;
        #pragma unroll
        for (int reg = 0; reg < 16; ++reg) {
            int row = 32 * r + (reg & 3) + 8 * (reg >> 2) + 4 * (lane >> 5);
            int col = 32 * cq + (lane & 31);
            myp[row * 64 + col] = acc[reg];
        }
        fsum[t] = csum;
        __syncthreads();
        if (t < 64)
            myp[4096 + t] = fsum[t] + fsum[t + 64] + fsum[t + 128] + fsum[t + 192];
    }
    __threadfence();
    gg.sync();

    // ---------------- phase 2: distributed reduce -> cov + means ----------------
    {
        float* msh = (float*)(smem + 49664);
        if (t < 64) {
            float su = 0.0f;
            for (int k = 0; k < BPB; ++k)
                su += partial[(size_t)(b * BPB + k) * PARTIAL_STRIDE + 4096 + t];
            float m = su / (float)HW_PX;
            msh[t] = m;
            if (j == 0) meanv[b * 64 + t] = m;
        }
        __syncthreads();
        const float invn = 1.0f / (float)(HW_PX - 1);
        const int e0 = (j * 4096) / BPB, e1 = ((j + 1) * 4096) / BPB;
        for (int e = e0 + t; e < e1; e += 256) {
            float su = 0.0f;
            for (int k = 0; k < BPB; ++k)
                su += partial[(size_t)(b * BPB + k) * PARTIAL_STRIDE + e];
            cov[b * 4096 + e] = (su - (float)HW_PX * msh[e >> 6] * msh[e & 63]) * invn;
        }
    }
    __threadfence();
    gg.sync();

    // ---------------- phase 3: Newton-Schulz (blocks 0..15) ----------------
    if (w < BATCH) {
        short* Yh = (short*)smem;
        short* Yl = (short*)(smem + 8192);
        short* Zh = (short*)(smem + 16384);
        short* Zl = (short*)(smem + 24576);
        short* Ph = (short*)(smem + 32768);
        short* Pl = (short*)(smem + 40960);
        float* csh = (float*)(smem + 49920);
        float* Cf = (float*)Ph;
        const int r = wave >> 1, cq = wave & 1;

        for (int e = t; e < 4096; e += 256)
            Cf[e] = cov[w * 4096 + e];
        __syncthreads();
        if (t == 0) {
            float tr = 0.0f;
            for (int i = 0; i < 64; ++i) tr += Cf[i * 64 + i];
            csh[0] = 64.0f / tr;
        }
        __syncthreads();
        const float invc = csh[0];
        for (int e = t; e < 4096; e += 256) {
            int row = e >> 6, col = e & 63;
            float y = Cf[e] * invc;
            unsigned short hi = bf16_rne(y);
            float lo = y - bf16_f32(hi);
            int idx = sw_idx(row, col);
            Yh[idx] = (short)hi; Yl[idx] = (short)bf16_rne(lo);
            Zh[idx] = (row == col) ? (short)0x3F80 : (short)0;
            Zl[idx] = 0;
        }
        __syncthreads();
        const int ra = 32 * r + (lane & 31);
        const int rb = 32 * cq + (lane & 31);
        for (int it = 0; it < 5; ++it) {
            f32x16 tacc;
            #pragma unroll
            for (int i = 0; i < 16; ++i) tacc[i] = 0.0f;
            mm_quad_hilo(tacc, Zh, Zl, Yh, Yl, ra, rb, lane);
            wb_hilo(Ph, Pl, tacc, r, cq, lane, -0.5f, 1.5f);
            __syncthreads();
            f32x16 ya, za;
            #pragma unroll
            for (int i = 0; i < 16; ++i) { ya[i] = 0.0f; za[i] = 0.0f; }
            mm_quad_hilo(ya, Yh, Yl, Ph, Pl, ra, rb, lane);
            mm_quad_hilo(za, Ph, Pl, Zh, Zl, ra, rb, lane);
            __syncthreads();
            wb_hilo(Yh, Yl, ya, r, cq, lane, 1.0f, 0.0f);
            wb_hilo(Zh, Zl, za, r, cq, lane, 1.0f, 0.0f);
            __syncthreads();
        }
        const float c = 1.0f / invc;
        const float sc = sqrtf(c);
        const float isc = 1.0f / sc;
        float* yo = Ym + w * 4096;
        float* zo = Zm + w * 4096;
        for (int e = t; e < 4096; e += 256) {
            int row = e >> 6, col = e & 63;
            int idx = sw_idx(row, col);
            yo[e] = (bf16_f32((unsigned short)Yh[idx]) + bf16_f32((unsigned short)Yl[idx])) * sc;
            zo[e] = (bf16_f32((unsigned short)Zh[idx]) + bf16_f32((unsigned short)Zl[idx])) * isc;
        }
    }
    __threadfence();
    gg.sync();

    // ---------------- phase 4: combine (blocks 0..15) ----------------
    if (w < BATCH) {
        short* Yh = (short*)smem;
        short* Yl = (short*)(smem + 8192);
        short* Zh = (short*)(smem + 16384);
        short* Zl = (short*)(smem + 24576);
        float* Mf = (float*)(smem + 32768);   // 64 x 66
        const int r = wave >> 1, cq = wave & 1;
        const int sb = perm[w];
        const float* yg = Ym + sb * 4096;
        const float* zg = Zm + w * 4096;
        for (int e = t; e < 4096; e += 256) {
            int row = e >> 6, col = e & 63;
            int idx = sw_idx(row, col);
            float y = yg[e];
            unsigned short hy = bf16_rne(y);
            Yh[idx] = (short)hy; Yl[idx] = (short)bf16_rne(y - bf16_f32(hy));
            float z = zg[e];
            unsigned short hz = bf16_rne(z);
            Zh[idx] = (short)hz; Zl[idx] = (short)bf16_rne(z - bf16_f32(hz));
        }
        __syncthreads();
        f32x16 acc;
        #pragma unroll
        for (int i = 0; i < 16; ++i) acc[i] = 0.0f;
        const int ra = 32 * r + (lane & 31);
        const int rb = 32 * cq + (lane & 31);
        mm_quad_hilo(acc, Yh, Yl, Zh, Zl, ra, rb, lane);
        const float al = alpha[w];
        float* Ab = Am + w * 4096;
        #pragma unroll
        for (int reg = 0; reg < 16; ++reg) {
            int row = 32 * r + (reg & 3) + 8 * (reg >> 2) + 4 * (lane >> 5);
            int col = 32 * cq + (lane & 31);
            float mv = acc[reg];
            Mf[row * 66 + col] = mv;
            Ab[row * 64 + col] = (1.0f - al) * mv + ((row == col) ? al : 0.0f);
        }
        __syncthreads();
        if (t < 64) {
            const float* mt = meanv + w * 64;
            const float* ms = meanv + sb * 64;
            float s = 0.0f;
            for (int k = 0; k < 64; ++k) s += Mf[t * 66 + k] * mt[k];
            ev[w * 64 + t] = (1.0f - al) * (ms[t] - s);
        }
    }
    __threadfence();
    gg.sync();

    // ---------------- phase 5: apply (transposed, reversed order, NT stores) ----------------
    {
        short* xs = (short*)smem;                 // [2][4096] bf16, swizzled [px][ch]
        const int pr = wave >> 1, c2 = wave & 1;
        const int t0 = (j * TPB) / BPB, t1 = ((j + 1) * TPB) / BPB;
        const size_t xb = (size_t)b * HW_PX * CH;
        const int ch_out = 32 * c2 + (lane & 31);
        const float* Ab = Am + b * 4096;
        bf16x8 bfrag[4];
        #pragma unroll
        for (int kc = 0; kc < 4; ++kc) {
            bf16x8 f;
            #pragma unroll
            for (int jj = 0; jj < 8; ++jj)
                f[jj] = (short)bf16_rne(Ab[ch_out * 64 + kc * 16 + (lane >> 5) * 8 + jj]);
            bfrag[kc] = f;
        }
        const float ebias = ev[b * 64 + ch_out];
        const int oct = t & 7, spx = t >> 3;
        auto stage2 = [&](int buf, int tile) {
            const size_t tb = xb + (size_t)tile * 64 * CH;
            #pragma unroll
            for (int p = 0; p < 2; ++p) {
                const int px = p * 32 + spx;
                const float* src = &x[tb + (size_t)px * CH + oct * 8];
                f32x4 v0 = *(const f32x4*)src;
                f32x4 v1 = *(const f32x4*)(src + 4);
                bf16x8 wv;
                #pragma unroll
                for (int jj = 0; jj < 4; ++jj) wv[jj] = (short)bf16_rne(v0[jj]);
                #pragma unroll
                for (int jj = 0; jj < 4; ++jj) wv[4 + jj] = (short)bf16_rne(v1[jj]);
                *(bf16x8*)&xs[buf * 4096 + px * 64 + ((oct ^ (px & 7)) << 3)] = wv;
            }
        };
        stage2(0, t1 - 1);
        __syncthreads();
        const int ra = 32 * pr + (lane & 31);
        const int nt = t1 - t0;
        #pragma unroll 1
        for (int k = 0; k < nt; ++k) {
            const int tile = t1 - 1 - k;
            const int cur = k & 1;
            if (k + 1 < nt) stage2(cur ^ 1, tile - 1);
            f32x16 acc;
            #pragma unroll
            for (int i = 0; i < 16; ++i) acc[i] = ebias;
            #pragma unroll
            for (int kc = 0; kc < 4; ++kc) {
                bf16x8 ah = ld_frag8(xs + cur * 4096, ra, kc * 2 + (lane >> 5));
                acc = __builtin_amdgcn_mfma_f32_32x32x16_bf16(ah, bfrag[kc], acc, 0, 0, 0);
            }
            const size_t tb = xb + (size_t)tile * 64 * CH;
            #pragma unroll
            for (int reg = 0; reg < 16; ++reg) {
                const int px = 32 * pr + (reg & 3) + 8 * (reg >> 2) + 4 * (lane >> 5);
                // full 128B line per half-wave: NT store avoids L3 write-allocate,
                // keeping x resident for the remaining (reversed) reads.
                __builtin_nontemporal_store(acc[reg], &out[tb + (size_t)px * CH + ch_out]);
            }
            __syncthreads();
        }
    }
}

// ==================== fallback: proven round-5 path ====================
template<int NB1T>
__global__ __launch_bounds__(256, 6) void pass1_cov(const float* __restrict__ x,
                                                    float* __restrict__ partial) {
    constexpr int PX1T = HW_PX / NB1T;
    constexpr int NT1T = PX1T / 64;
    const int blk = blockIdx.x;
    const int b = blk / NB1T;
    const int chunk = blk % NB1T;
    const size_t base = (size_t)b * HW_PX * CH + (size_t)chunk * PX1T * CH;
    const int t = threadIdx.x;
    const int lane = t & 63;
    const int wave = t >> 6;
    const int r = wave >> 1, cq = wave & 1;
    const int s_ch = t & 63;
    const int s_og = t >> 6;
    __shared__ __align__(16) short xs[2][4096];
    __shared__ float fsum[256];
    f32x16 acc;
    #pragma unroll
    for (int i = 0; i < 16; ++i) acc[i] = 0.0f;
    float csum = 0.0f;
    {
        const size_t tb = base;
        #pragma unroll
        for (int p = 0; p < 2; ++p) {
            const int o = s_og + 4 * p;
            bf16x8 wv;
            #pragma unroll
            for (int jj = 0; jj < 8; ++jj) {
                float v = x[tb + (size_t)(o * 8 + jj) * CH + s_ch];
                csum += v;
                wv[jj] = (short)bf16_rne(v);
            }
            *(bf16x8*)&xs[0][s_ch * 64 + ((o ^ (s_ch & 7)) << 3)] = wv;
        }
    }
    __syncthreads();
    const int ra = 32 * r + (lane & 31);
    const int rb = 32 * cq + (lane & 31);
    for (int tile = 0; tile < NT1T; ++tile) {
        const int cur = tile & 1;
        if (tile + 1 < NT1T) {
            const size_t tb = base + (size_t)(tile + 1) * 64 * CH;
            const int nb = cur ^ 1;
            #pragma unroll
            for (int p = 0; p < 2; ++p) {
                const int o = s_og + 4 * p;
                bf16x8 wv;
                #pragma unroll
                for (int jj = 0; jj < 8; ++jj) {
                    float v = x[tb + (size_t)(o * 8 + jj) * CH + s_ch];
                    csum += v;
                    wv[jj] = (short)bf16_rne(v);
                }
                *(bf16x8*)&xs[nb][s_ch * 64 + ((o ^ (s_ch & 7)) << 3)] = wv;
            }
        }
        #pragma unroll
        for (int kc = 0; kc < 4; ++kc) {
            const int o = kc * 2 + (lane >> 5);
            bf16x8 af = *(const bf16x8*)&xs[cur][ra * 64 + ((o ^ (ra & 7)) << 3)];
            bf16x8 bg = *(const bf16x8*)&xs[cur][rb * 64 + ((o ^ (rb & 7)) << 3)];
            acc = __builtin_amdgcn_mfma_f32_32x32x16_bf16(af, bg, acc, 0, 0, 0);
        }
        __syncthreads();
    }
    float* myp = partial + (size_t)blk * PARTIAL_STRIDE;
    #pragma unroll
    for (int reg = 0; reg < 16; ++reg) {
        int row = 32 * r + (reg & 3) + 8 * (reg >> 2) + 4 * (lane >> 5);
        int col = 32 * cq + (lane & 31);
        myp[row * 64 + col] = acc[reg];
    }
    fsum[t] = csum;
    __syncthreads();
    if (t < 64)
        myp[4096 + t] = fsum[t] + fsum[t + 64] + fsum[t + 128] + fsum[t + 192];
}

template<int NB1T>
__global__ __launch_bounds__(256) void reduce_cov(const float* __restrict__ partial,
                                                  float* __restrict__ meanv,
                                                  float* __restrict__ cov) {
    const int b = blockIdx.x >> 4;
    const int s = blockIdx.x & 15;
    const int t = threadIdx.x;
    __shared__ float msh[64];
    if (t < 64) {
        float su = 0.0f;
        for (int k = 0; k < NB1T; ++k)
            su += partial[(size_t)(b * NB1T + k) * PARTIAL_STRIDE + 4096 + t];
        float m = su / (float)HW_PX;
        msh[t] = m;
        if (s == 0) meanv[b * 64 + t] = m;
    }
    __syncthreads();
    const float invn = 1.0f / (float)(HW_PX - 1);
    const int e = s * 256 + t;
    float su = 0.0f;
    for (int k = 0; k < NB1T; ++k)
        su += partial[(size_t)(b * NB1T + k) * PARTIAL_STRIDE + e];
    const int i = e >> 6, jj = e & 63;
    cov[b * 4096 + e] = (su - (float)HW_PX * msh[i] * msh[jj]) * invn;
}

__global__ __launch_bounds__(256) void ns_sqrt(
        const float* __restrict__ cov,
        float* __restrict__ Ym, float* __restrict__ Zm) {
    const int b = blockIdx.x;
    const int t = threadIdx.x;
    const int lane = t & 63;
    const int wave = t >> 6;
    const int r = wave >> 1, cq = wave & 1;
    __shared__ __align__(16) short Yh[4096], Yl[4096], Zh[4096], Zl[4096], Ph[4096], Pl[4096];
    __shared__ float csh;
    float* Cf = (float*)Ph;
    for (int e = t; e < 4096; e += 256)
        Cf[e] = cov[b * 4096 + e];
    __syncthreads();
    if (t == 0) {
        float tr = 0.0f;
        for (int i = 0; i < 64; ++i) tr += Cf[i * 64 + i];
        csh = 64.0f / tr;
    }
    __syncthreads();
    const float invc = csh;
    for (int e = t; e < 4096; e += 256) {
        int row = e >> 6, col = e & 63;
        float y = Cf[e] * invc;
        unsigned short hi = bf16_rne(y);
        float lo = y - bf16_f32(hi);
        int idx = sw_idx(row, col);
        Yh[idx] = (short)hi; Yl[idx] = (short)bf16_rne(lo);
        Zh[idx] = (row == col) ? (short)0x3F80 : (short)0;
        Zl[idx] = 0;
    }
    __syncthreads();
    const int ra = 32 * r + (lane & 31);
    const int rb = 32 * cq + (lane & 31);
    for (int it = 0; it < 5; ++it) {
        f32x16 tacc;
        #pragma unroll
        for (int i = 0; i < 16; ++i) tacc[i] = 0.0f;
        mm_quad_hilo(tacc, Zh, Zl, Yh, Yl, ra, rb, lane);
        wb_hilo(Ph, Pl, tacc, r, cq, lane, -0.5f, 1.5f);
        __syncthreads();
        f32x16 ya, za;
        #pragma unroll
        for (int i = 0; i < 16; ++i) { ya[i] = 0.0f; za[i] = 0.0f; }
        mm_quad_hilo(ya, Yh, Yl, Ph, Pl, ra, rb, lane);
        mm_quad_hilo(za, Ph, Pl, Zh, Zl, ra, rb, lane);
        __syncthreads();
        wb_hilo(Yh, Yl, ya, r, cq, lane, 1.0f, 0.0f);
        wb_hilo(Zh, Zl, za, r, cq, lane, 1.0f, 0.0f);
        __syncthreads();
    }
    const float c = 1.0f / invc;
    const float sc = sqrtf(c);
    const float isc = 1.0f / sc;
    float* yo = Ym + b * 4096;
    float* zo = Zm + b * 4096;
    for (int e = t; e < 4096; e += 256) {
        int row = e >> 6, col = e & 63;
        int idx = sw_idx(row, col);
        yo[e] = (bf16_f32((unsigned short)Yh[idx]) + bf16_f32((unsigned short)Yl[idx])) * sc;
        zo[e] = (bf16_f32((unsigned short)Zh[idx]) + bf16_f32((unsigned short)Zl[idx])) * isc;
    }
}

__global__ __launch_bounds__(256) void combine(
        const float* __restrict__ Ym, const float* __restrict__ Zm,
        const float* __restrict__ meanv,
        const int* __restrict__ perm, const float* __restrict__ alpha,
        float* __restrict__ Amat, float* __restrict__ evec) {
    const int b = blockIdx.x;
    const int t = threadIdx.x;
    const int lane = t & 63;
    const int wave = t >> 6;
    const int r = wave >> 1, cq = wave & 1;
    const int sb = perm[b];
    __shared__ __align__(16) short Yh[4096], Yl[4096], Zh[4096], Zl[4096];
    __shared__ float Mf[64 * 66];
    const float* yg = Ym + sb * 4096;
    const float* zg = Zm + b * 4096;
    for (int e = t; e < 4096; e += 256) {
        int row = e >> 6, col = e & 63;
        int idx = sw_idx(row, col);
        float y = yg[e];
        unsigned short hy = bf16_rne(y);
        Yh[idx] = (short)hy; Yl[idx] = (short)bf16_rne(y - bf16_f32(hy));
        float z = zg[e];
        unsigned short hz = bf16_rne(z);
        Zh[idx] = (short)hz; Zl[idx] = (short)bf16_rne(z - bf16_f32(hz));
    }
    __syncthreads();
    f32x16 acc;
    #pragma unroll
    for (int i = 0; i < 16; ++i) acc[i] = 0.0f;
    const int ra = 32 * r + (lane & 31);
    const int rb = 32 * cq + (lane & 31);
    mm_quad_hilo(acc, Yh, Yl, Zh, Zl, ra, rb, lane);
    const float al = alpha[b];
    float* Ab = Amat + b * 4096;
    #pragma unroll
    for (int reg = 0; reg < 16; ++reg) {
        int row = 32 * r + (reg & 3) + 8 * (reg >> 2) + 4 * (lane >> 5);
        int col = 32 * cq + (lane & 31);
        float mv = acc[reg];
        Mf[row * 66 + col] = mv;
        Ab[row * 64 + col] = (1.0f - al) * mv + ((row == col) ? al : 0.0f);
    }
    __syncthreads();
    if (t < 64) {
        const float* mt = meanv + b * 64;
        const float* ms = meanv + sb * 64;
        float s = 0.0f;
        for (int k = 0; k < 64; ++k) s += Mf[t * 66 + k] * mt[k];
        evec[b * 64 + t] = (1.0f - al) * (ms[t] - s);
    }
}

__global__ __launch_bounds__(256, 8) void pass2_apply(const float* __restrict__ x,
                                                      const float* __restrict__ Amat,
                                                      const float* __restrict__ evec,
                                                      float* __restrict__ out) {
    const int blk = blockIdx.x;
    const int b = blk / NB2;
    const int chunk = blk % NB2;
    const int t = threadIdx.x;
    const int lane = t & 63;
    const int wave = t >> 6;
    const int pr = wave >> 1;
    const int c2 = wave & 1;
    const size_t base = (size_t)b * HW_PX * CH + (size_t)chunk * PX2 * CH;
    __shared__ __align__(16) short xs[2][TPX * 64];
    const int ch_out = 32 * c2 + (lane & 31);
    const float* Ab = Amat + b * 4096;
    bf16x8 bfrag[4];
    #pragma unroll
    for (int kc = 0; kc < 4; ++kc) {
        bf16x8 f;
        #pragma unroll
        for (int jj = 0; jj < 8; ++jj)
            f[jj] = (short)bf16_rne(Ab[ch_out * 64 + kc * 16 + (lane >> 5) * 8 + jj]);
        bfrag[kc] = f;
    }
    const float ebias = evec[b * 64 + ch_out];
    const int oct = t & 7;
    const int spx = t >> 3;
    auto stage = [&](int buf, int tile) {
        const size_t tb = base + (size_t)tile * TPX * CH;
        #pragma unroll
        for (int p = 0; p < 2; ++p) {
            const int px = p * 32 + spx;
            const float* src = &x[tb + (size_t)px * CH + oct * 8];
            f32x4 v0 = *(const f32x4*)src;
            f32x4 v1 = *(const f32x4*)(src + 4);
            bf16x8 wv;
            #pragma unroll
            for (int jj = 0; jj < 4; ++jj) wv[jj] = (short)bf16_rne(v0[jj]);
            #pragma unroll
            for (int jj = 0; jj < 4; ++jj) wv[4 + jj] = (short)bf16_rne(v1[jj]);
            *(bf16x8*)&xs[buf][px * 64 + ((oct ^ (px & 7)) << 3)] = wv;
        }
    };
    stage(0, 0);
    __syncthreads();
    const int ra = 32 * pr + (lane & 31);
    #pragma unroll 1
    for (int tile = 0; tile < NT2; ++tile) {
        const int cur = tile & 1;
        if (tile + 1 < NT2) stage(cur ^ 1, tile + 1);
        f32x16 acc;
        #pragma unroll
        for (int i = 0; i < 16; ++i) acc[i] = ebias;
        #pragma unroll
        for (int kc = 0; kc < 4; ++kc) {
            bf16x8 ah = ld_frag8(&xs[cur][0], ra, kc * 2 + (lane >> 5));
            acc = __builtin_amdgcn_mfma_f32_32x32x16_bf16(ah, bfrag[kc], acc, 0, 0, 0);
        }
        const size_t tb = base + (size_t)tile * TPX * CH;
        #pragma unroll
        for (int reg = 0; reg < 16; ++reg) {
            const int px = 32 * pr + (reg & 3) + 8 * (reg >> 2) + 4 * (lane >> 5);
            out[tb + (size_t)px * CH + ch_out] = acc[reg];
        }
        __syncthreads();
    }
}

// ==================== launcher ====================
extern "C" void kernel_launch(void* const* d_in, const int* in_sizes, int n_in,
                              void* d_out, int out_size, void* d_ws, size_t ws_size,
                              hipStream_t stream) {
    (void)in_sizes; (void)n_in; (void)out_size;
    const float* x     = (const float*)d_in[0];
    const int*   perm  = (const int*)d_in[1];
    const float* alpha = (const float*)d_in[2];
    float* out = (float*)d_out;
    float* ws  = (float*)d_ws;

    // ---- try the fused cooperative path ----
    {
        float* partial = ws;
        float* cov   = partial + (size_t)GRIDF * PARTIAL_STRIDE;
        float* meanv = cov + BATCH * 4096;
        float* Ym    = meanv + BATCH * 64;
        float* Zm    = Ym + BATCH * 4096;
        float* Am    = Zm + BATCH * 4096;
        float* ev    = Am + BATCH * 4096;
        const size_t need_f = ((size_t)GRIDF * PARTIAL_STRIDE
                             + (size_t)BATCH * (4096 * 4 + 128)) * sizeof(float);
        int dev = 0;
        hipGetDevice(&dev);
        int coop = 0;
        hipDeviceGetAttribute(&coop, hipDeviceAttributeCooperativeLaunch, dev);
        int ncu = 0;
        hipDeviceGetAttribute(&ncu, hipDeviceAttributeMultiprocessorCount, dev);
        int maxb = 0;
        hipOccupancyMaxActiveBlocksPerMultiprocessor(&maxb, wct_fused, 256, 0);
        if (coop && ws_size >= need_f && maxb >= 1 && (size_t)maxb * (size_t)ncu >= GRIDF) {
            void* args[] = { (void*)&x, (void*)&perm, (void*)&alpha, (void*)&out,
                             (void*)&partial, (void*)&cov, (void*)&meanv,
                             (void*)&Ym, (void*)&Zm, (void*)&Am, (void*)&ev };
            hipError_t e = hipLaunchCooperativeKernel((const void*)wct_fused,
                               dim3(GRIDF), dim3(256), args, 0, stream);
            if (e == hipSuccess) return;
        }
    }

    // ---- fallback: proven round-5 five-kernel path ----
    const size_t rest_elems = (size_t)BATCH * 4096
                            + (size_t)BATCH * 64
                            + (size_t)BATCH * 4096 * 3
                            + (size_t)BATCH * 64;
    auto need = [&](int nb) {
        return ((size_t)BATCH * nb * PARTIAL_STRIDE + rest_elems) * sizeof(float);
    };
    const int nb1 = (ws_size >= need(128)) ? 128 : (ws_size >= need(64)) ? 64 : 32;
    float* partial = ws;
    float* cov     = partial + (size_t)BATCH * nb1 * PARTIAL_STRIDE;
    float* meanv   = cov + BATCH * 4096;
    float* Ym      = meanv + BATCH * 64;
    float* Zm      = Ym + BATCH * 4096;
    float* Am      = Zm + BATCH * 4096;
    float* ev      = Am + BATCH * 4096;
    if (nb1 == 128) {
        pass1_cov<128> <<<BATCH * 128, 256, 0, stream>>>(x, partial);
        reduce_cov<128><<<BATCH * 16,  256, 0, stream>>>(partial, meanv, cov);
    } else if (nb1 == 64) {
        pass1_cov<64>  <<<BATCH * 64,  256, 0, stream>>>(x, partial);
        reduce_cov<64> <<<BATCH * 16,  256, 0, stream>>>(partial, meanv, cov);
    } else {
        pass1_cov<32>  <<<BATCH * 32,  256, 0, stream>>>(x, partial);
        reduce_cov<32> <<<BATCH * 16,  256, 0, stream>>>(partial, meanv, cov);
    }
    ns_sqrt    <<<BATCH,       256, 0, stream>>>(cov, Ym, Zm);
    combine    <<<BATCH,       256, 0, stream>>>(Ym, Zm, meanv, perm, alpha, Am, ev);
    pass2_apply<<<BATCH * NB2, 256, 0, stream>>>(x, Am, ev, out);
}